// Round 7
// baseline (200.514 us; speedup 1.0000x reference)
//
#include <hip/hip_runtime.h>
#include <hip/hip_bf16.h>

// MoE top-2 dispatch -> pair-binned grouped GEMM (bf16 MFMA) -> single-store combine.
// 3 launches:
//   0. memsetAsync cnt[64]
//   1. prep (role-split): route (LDS-histogram) | cvt_x (bf16) | cvt_wt (transpose)
//   2. moe_gemm: 8-phase counted-vmcnt schedule (m201 port):
//      128x256 tile, 8 waves (2Mx4N, 64x64/wave), K processed in 64 half-tiles
//      of 32; 4 half-buffers in LDS; per phase: stage(h+3) || 8 ds_read || bar
//      -> lgkmcnt(0) -> setprio(1) -> 16 MFMA -> setprio(0) -> vmcnt(6) -> bar.
//      3 half-tiles always in flight; vmcnt never drained in the main loop.
//      pass0 = x*W[e1]; acc *= r=g1/g2; pass1 += x*W[e2]; out = s*(acc+r*b1+b2).

#define TOK 16384
#define DD  1024
#define OO  1024
#define NE  8
#define NBIN 64
#define MAXT 192   // sum ceil(cnt_p/128) <= 16384/128 + 64 = 192; 192%8==0 (XCD)
#define BM  128
#define BN  256
#define BKH 32                 // half K-tile
#define A_HALF (BM * BKH)      // 4096 elems = 8 KB
#define B_HALF (BN * BKH)      // 8192 elems = 16 KB

typedef __bf16 bf16x8 __attribute__((ext_vector_type(8)));
typedef float  f32x4  __attribute__((ext_vector_type(4)));

__device__ __forceinline__ unsigned short f2bf(float f) {
  unsigned u = __float_as_uint(f);
  u += 0x7fffu + ((u >> 16) & 1u);   // RNE
  return (unsigned short)(u >> 16);
}

__device__ __forceinline__ void gload_lds16(const void* g, void* l) {
  __builtin_amdgcn_global_load_lds(
      (const __attribute__((address_space(1))) void*)g,
      (__attribute__((address_space(3))) void*)l, 16, 0, 0);
}

// end-of-phase: counted vmcnt (stage h+1 landed), then barrier; pin order.
#define ENDP(N) do { \
    asm volatile("s_waitcnt vmcnt(" #N ")" ::: "memory"); \
    __builtin_amdgcn_s_barrier(); \
    __builtin_amdgcn_sched_barrier(0); \
  } while (0)

// ---------------- fused prep (unchanged, proven ~23us incl. overheads) --------
#define PREP_ROUTE_B 64
#define PREP_CVTX_B  4096
#define PREP_CVTW_B  2048

__global__ __launch_bounds__(256) void prep(
    const float* __restrict__ x, const float* __restrict__ gates,
    const float* __restrict__ W,
    unsigned short* __restrict__ xs, unsigned short* __restrict__ wtb,
    int* __restrict__ cnt, int* __restrict__ idx, float2* __restrict__ gp) {
  __shared__ float tile[64][65];
  int bid = blockIdx.x;

  if (bid < PREP_ROUTE_B) {
    __shared__ int h[NBIN];
    __shared__ int gbase[NBIN];
    if (threadIdx.x < NBIN) h[threadIdx.x] = 0;
    __syncthreads();
    int i = bid * 256 + threadIdx.x;
    int e1 = -1, e2 = -1; float g1 = 0.f, g2 = 0.f;
#pragma unroll
    for (int e = 0; e < NE; ++e) {
      float g = gates[i * NE + e];
      if (g > 0.f) { if (e1 < 0) { e1 = e; g1 = g; } else if (e2 < 0) { e2 = e; g2 = g; } }
    }
    float r, s; int pid = 0, rank = 0, valid = (e1 >= 0);
    if (valid) {
      if (e2 < 0) { e2 = e1; r = 1.f; s = 0.5f * g1; }
      else        { r = g1 / g2; s = g2; }
      pid = e1 * NE + e2;
      rank = atomicAdd(&h[pid], 1);
    } else { r = 0.f; s = 0.f; }
    __syncthreads();
    if (threadIdx.x < NBIN && h[threadIdx.x] > 0)
      gbase[threadIdx.x] = atomicAdd(cnt + threadIdx.x, h[threadIdx.x]);
    __syncthreads();
    if (valid) {
      int pos = gbase[pid] + rank;
      idx[pid * TOK + pos] = i;
      gp[(size_t)pid * TOK + pos] = make_float2(r, s);
    }

  } else if (bid < PREP_ROUTE_B + PREP_CVTX_B) {
    size_t base = (size_t)(bid - PREP_ROUTE_B) * 1024 + threadIdx.x;  // float4 units
    const float4* xp = (const float4*)x;
#pragma unroll
    for (int q = 0; q < 4; ++q) {
      float4 v = xp[base + q * 256];
      alignas(8) unsigned short o4[4] = {f2bf(v.x), f2bf(v.y), f2bf(v.z), f2bf(v.w)};
      *(uint2*)(xs + (base + q * 256) * 4) = *(const uint2*)o4;
    }

  } else {
    int wb = bid - (PREP_ROUTE_B + PREP_CVTX_B);
    int e = wb >> 8, tt = wb & 255;
    int d0 = (tt >> 4) * 64, o0 = (tt & 15) * 64;
    const float* src = W + ((size_t)e << 20) + (size_t)d0 * OO + o0;
    for (int i = threadIdx.x; i < 1024; i += 256) {
      int r = i >> 4, c4 = (i & 15) * 4;
      float4 v = *(const float4*)(src + (size_t)r * OO + c4);
      tile[r][c4 + 0] = v.x; tile[r][c4 + 1] = v.y;
      tile[r][c4 + 2] = v.z; tile[r][c4 + 3] = v.w;
    }
    __syncthreads();
    unsigned short* dst = wtb + ((size_t)e << 20) + (size_t)o0 * DD + d0;
    for (int i = threadIdx.x; i < 512; i += 256) {
      int o = i >> 3, d8 = (i & 7) * 8;
      alignas(16) unsigned short w8[8];
#pragma unroll
      for (int j = 0; j < 8; ++j) w8[j] = f2bf(tile[d8 + j][o]);
      *(uint4*)(dst + (size_t)o * DD + d8) = *(const uint4*)w8;
    }
  }
}

// ---------------- grouped GEMM: 8-phase counted-vmcnt ----------------
__global__ __launch_bounds__(512, 2) void moe_gemm(
    const unsigned short* __restrict__ xs,
    const unsigned short* __restrict__ wtb, const int* __restrict__ idx,
    const float2* __restrict__ gp, const int* __restrict__ cnt,
    const float* __restrict__ bias, float* __restrict__ out) {
  __shared__ unsigned short As[4 * A_HALF];   // 32 KB: 4 half-buffers
  __shared__ unsigned short Bs[4 * B_HALF];   // 64 KB
  __shared__ int    rowsS[BM];
  __shared__ float2 gS[BM];
  __shared__ int    sPid, sLt, sCnt;

  // derive (pid, local tile) from cnt[] with a 64-lane prefix scan
  if (threadIdx.x < 64) {
    int lane = threadIdx.x;
    if (lane == 0) sPid = -1;
    int c = cnt[lane];
    int n = (c + BM - 1) >> 7;
    int pre = n;
#pragma unroll
    for (int o = 1; o < 64; o <<= 1) {
      int v = __shfl_up(pre, o);
      if (lane >= o) pre += v;
    }
    int lo = pre - n;
    int tb = blockIdx.x;
    if (tb >= lo && tb < pre) { sPid = lane; sLt = tb - lo; sCnt = c; }
  }
  __syncthreads();
  int pid = sPid;
  if (pid < 0) return;
  int lt = sLt, cntv = sCnt;
  int e1 = pid >> 3, e2 = pid & 7;
  int n0 = blockIdx.y * BN;

  int t = threadIdx.x, lane = t & 63, w = t >> 6;   // w in 0..7
  if (t < BM) {
    int slot = lt * BM + t;
    int tok = 0; float2 g = make_float2(0.f, 0.f);
    if (slot < cntv) { tok = idx[pid * TOK + slot]; g = gp[(size_t)pid * TOK + slot]; }
    rowsS[t] = tok; gS[t] = g;
  }
  __syncthreads();   // drains all prior vmem; vmcnt==0 from here

  // ---- stage sources (pre-swizzled global chunk: chunk' = chunk ^ ((row>>1)&3),
  //      64B rows / 4 chunks of 16B; LDS dest stays linear — same involution on read)
  int srcChunk = (((lane & 3) ^ ((lane >> 3) & 3)) << 3);   // elems
  int rA = w * 16 + (lane >> 2);                            // A row this lane stages
  const unsigned short* aSrc = xs + (size_t)rowsS[rA] * DD + srcChunk;
  int rB = w * 32 + (lane >> 2);                            // B rows: +0 and +16
  const unsigned short* bSrc = wtb + ((size_t)e1 * OO + n0 + rB) * DD + srcChunk;
  const ptrdiff_t bAdvE = (ptrdiff_t)(e2 - e1) * OO * DD;   // W[e1] -> W[e2]

  int wm = w >> 2, wn = w & 3;           // 2M x 4N wave grid
  int hi = lane >> 4, lo = lane & 15;
  int swz = ((hi ^ ((lo >> 1) & 3)) << 3);                  // read-side involution
  int aOff[4], bOff[4];
#pragma unroll
  for (int m = 0; m < 4; ++m) aOff[m] = (wm * 64 + m * 16 + lo) * BKH + swz;
#pragma unroll
  for (int n = 0; n < 4; ++n) bOff[n] = (wn * 64 + n * 16 + lo) * BKH + swz;

  f32x4 acc[4][4] = {};

  // stage half h (h = 0..63; pass = h>>5, k-elems = (h&31)*32): 3 gloads/wave
  auto STAGE = [&](int h) {
    int hb = h & 3;
    size_t ko = (size_t)(h & 31) * BKH;
    const unsigned short* a = aSrc + ko;
    const unsigned short* b = bSrc + ko + ((h >= 32) ? bAdvE : (ptrdiff_t)0);
    gload_lds16(a, (unsigned short*)As + hb * A_HALF + w * 512);
    gload_lds16(b, (unsigned short*)Bs + hb * B_HALF + w * 1024);
    gload_lds16(b + (size_t)16 * DD, (unsigned short*)Bs + hb * B_HALF + w * 1024 + 512);
  };

  // one phase: stage(h+3) || 8 ds_read || bar -> lgkm(0) -> prio -> 16 MFMA -> prio
  auto PHASE = [&](int h, bool stg) {
    if (stg) STAGE(h + 3);
    int hb = h & 3;
    const unsigned short* Ab = As + hb * A_HALF;
    const unsigned short* Bb = Bs + hb * B_HALF;
    bf16x8 af[4], bv[4];
#pragma unroll
    for (int m = 0; m < 4; ++m) af[m] = *(const bf16x8*)(Ab + aOff[m]);
#pragma unroll
    for (int n = 0; n < 4; ++n) bv[n] = *(const bf16x8*)(Bb + bOff[n]);
    __builtin_amdgcn_s_barrier();
    asm volatile("s_waitcnt lgkmcnt(0)" ::: "memory");
    __builtin_amdgcn_sched_barrier(0);
    __builtin_amdgcn_s_setprio(1);
#pragma unroll
    for (int m = 0; m < 4; ++m)
#pragma unroll
      for (int n = 0; n < 4; ++n)
        acc[m][n] = __builtin_amdgcn_mfma_f32_16x16x32_bf16(af[m], bv[n], acc[m][n], 0, 0, 0);
    __builtin_amdgcn_s_setprio(0);
    __builtin_amdgcn_sched_barrier(0);
  };

  // prologue: 3 half-tiles in flight (9 loads); confirm stage(0) -> 6 remain
  STAGE(0); STAGE(1); STAGE(2);
  ENDP(6);

#pragma unroll 1
  for (int h = 0; h < 31; ++h) { PHASE(h, true); ENDP(6); }
  PHASE(31, true); ENDP(6);
  // pass boundary: acc := r*(x*W1); pass 2 adds x*W2
#pragma unroll
  for (int m = 0; m < 4; ++m) {
    float rr[4];
#pragma unroll
    for (int j = 0; j < 4; ++j) rr[j] = gS[wm * 64 + m * 16 + hi * 4 + j].x;
#pragma unroll
    for (int n = 0; n < 4; ++n)
#pragma unroll
      for (int j = 0; j < 4; ++j) acc[m][n][j] *= rr[j];
  }
#pragma unroll 1
  for (int h = 32; h <= 60; ++h) { PHASE(h, true); ENDP(6); }
  PHASE(61, false); ENDP(3);
  PHASE(62, false); ENDP(0);
  PHASE(63, false);

  // epilogue: out = s*(acc + r*b1 + b2)
  const float* b1 = bias + e1 * OO;
  const float* b2 = bias + e2 * OO;
  float b1v[4], b2v[4];
#pragma unroll
  for (int n = 0; n < 4; ++n) {
    int col = n0 + wn * 64 + n * 16 + lo;
    b1v[n] = b1[col]; b2v[n] = b2[col];
  }
#pragma unroll
  for (int m = 0; m < 4; ++m) {
#pragma unroll
    for (int j = 0; j < 4; ++j) {
      int rl = wm * 64 + m * 16 + hi * 4 + j;   // C/D: row=(lane>>4)*4+reg, col=lane&15
      int slot = lt * BM + rl;
      if (slot < cntv) {
        float2 g = gS[rl];
        float* orow = out + (size_t)rowsS[rl] * OO + n0 + wn * 64 + lo;
#pragma unroll
        for (int n = 0; n < 4; ++n)
          orow[n * 16] = g.y * (acc[m][n][j] + g.x * b1v[n] + b2v[n]);
      }
    }
  }
}

extern "C" void kernel_launch(void* const* d_in, const int* in_sizes, int n_in,
                              void* d_out, int out_size, void* d_ws, size_t ws_size,
                              hipStream_t stream) {
  const float* x     = (const float*)d_in[0];
  const float* gates = (const float*)d_in[1];
  const float* W     = (const float*)d_in[2];
  const float* bias  = (const float*)d_in[3];
  float* out = (float*)d_out;

  char* ws = (char*)d_ws;
  size_t off = 0;
  unsigned short* xs  = (unsigned short*)(ws + off); off += (size_t)TOK * DD * 2;
  unsigned short* wtb = (unsigned short*)(ws + off); off += (size_t)NE * DD * OO * 2;
  int*    idx  = (int*)(ws + off);    off += (size_t)NBIN * TOK * 4;
  float2* gp   = (float2*)(ws + off); off += (size_t)NBIN * TOK * 8;
  int*    cnt  = (int*)(ws + off);    off += NBIN * 4;
  if (ws_size < off) return;  // insufficient scratch (~60.5 MB needed)

  hipMemsetAsync(cnt, 0, NBIN * 4, stream);
  prep<<<PREP_ROUTE_B + PREP_CVTX_B + PREP_CVTW_B, 256, 0, stream>>>(
      x, gates, W, xs, wtb, cnt, idx, gp);
  dim3 gg(MAXT, OO / BN, 1);   // tile in x: 192%8==0 -> col-blocks share XCD
  moe_gemm<<<gg, 512, 0, stream>>>(xs, wtb, idx, gp, cnt, bias, out);
}

// Round 8
// 144.278 us; speedup vs baseline: 1.3898x; 1.3898x over previous
//
#include <hip/hip_runtime.h>
#include <hip/hip_bf16.h>

// MoE top-2 dispatch -> pair-binned grouped GEMM (bf16 MFMA) -> single-store combine.
// 3 launches:
//   0. memsetAsync cnt[64]
//   1. prep (role-split): route (LDS-histogram) | cvt_x (bf16) | cvt_wt (transpose)
//   2. moe_gemm: 8-phase counted-vmcnt schedule (m201 port, FIXED phase order):
//      128x256 tile, 8 waves (2Mx4N, 64x64/wave), 64 half-tiles of K=32;
//      4 half-buffers; per phase: 8 asm ds_read_b128 (compiler-opaque: no
//      auto-vmcnt against in-flight global_load_lds) -> stage(h+3) ->
//      barrier -> lgkmcnt(0)+sched_barrier -> setprio(1) 16 MFMA setprio(0)
//      -> vmcnt(6) -> barrier.  vmcnt never 0 in the main loop.
//      R7 bug: stage was issued BEFORE the ds_reads; compiler inserted a vmcnt
//      drain before the (aliasing-unprovable) ds_reads -> ~2700cyc stall/phase.

#define TOK 16384
#define DD  1024
#define OO  1024
#define NE  8
#define NBIN 64
#define MAXT 192   // sum ceil(cnt_p/128) <= 16384/128 + 64 = 192; 192%8==0 (XCD)
#define BM  128
#define BN  256
#define BKH 32                 // half K-tile (elems)
#define A_HALF (BM * BKH)      // 4096 elems = 8 KB
#define B_HALF (BN * BKH)      // 8192 elems = 16 KB

typedef __bf16 bf16x8 __attribute__((ext_vector_type(8)));
typedef float  f32x4  __attribute__((ext_vector_type(4)));
typedef int    i32x4  __attribute__((ext_vector_type(4)));

union BU { i32x4 i; bf16x8 b; };

__device__ __forceinline__ unsigned short f2bf(float f) {
  unsigned u = __float_as_uint(f);
  u += 0x7fffu + ((u >> 16) & 1u);   // RNE
  return (unsigned short)(u >> 16);
}

__device__ __forceinline__ void gload_lds16(const void* g, void* l) {
  __builtin_amdgcn_global_load_lds(
      (const __attribute__((address_space(1))) void*)g,
      (__attribute__((address_space(3))) void*)l, 16, 0, 0);
}

// compiler-opaque LDS read: no operand-less memory effects -> the waitcnt pass
// cannot attach vmcnt waits to it; hazards are managed manually (barrier+vmcnt).
__device__ __forceinline__ bf16x8 ds_read_b128_bf16(unsigned addr) {
  BU u;
  asm volatile("ds_read_b128 %0, %1" : "=v"(u.i) : "v"(addr));
  return u.b;
}

// end-of-phase: counted vmcnt (stage h+1 landed on every wave), then barrier.
#define ENDP(N) do { \
    asm volatile("s_waitcnt vmcnt(" #N ")" ::: "memory"); \
    __builtin_amdgcn_s_barrier(); \
    __builtin_amdgcn_sched_barrier(0); \
  } while (0)

// ---------------- fused prep (proven) ----------------
#define PREP_ROUTE_B 64
#define PREP_CVTX_B  4096
#define PREP_CVTW_B  2048

__global__ __launch_bounds__(256) void prep(
    const float* __restrict__ x, const float* __restrict__ gates,
    const float* __restrict__ W,
    unsigned short* __restrict__ xs, unsigned short* __restrict__ wtb,
    int* __restrict__ cnt, int* __restrict__ idx, float2* __restrict__ gp) {
  __shared__ float tile[64][65];
  int bid = blockIdx.x;

  if (bid < PREP_ROUTE_B) {
    __shared__ int h[NBIN];
    __shared__ int gbase[NBIN];
    if (threadIdx.x < NBIN) h[threadIdx.x] = 0;
    __syncthreads();
    int i = bid * 256 + threadIdx.x;
    int e1 = -1, e2 = -1; float g1 = 0.f, g2 = 0.f;
#pragma unroll
    for (int e = 0; e < NE; ++e) {
      float g = gates[i * NE + e];
      if (g > 0.f) { if (e1 < 0) { e1 = e; g1 = g; } else if (e2 < 0) { e2 = e; g2 = g; } }
    }
    float r, s; int pid = 0, rank = 0, valid = (e1 >= 0);
    if (valid) {
      if (e2 < 0) { e2 = e1; r = 1.f; s = 0.5f * g1; }
      else        { r = g1 / g2; s = g2; }
      pid = e1 * NE + e2;
      rank = atomicAdd(&h[pid], 1);
    } else { r = 0.f; s = 0.f; }
    __syncthreads();
    if (threadIdx.x < NBIN && h[threadIdx.x] > 0)
      gbase[threadIdx.x] = atomicAdd(cnt + threadIdx.x, h[threadIdx.x]);
    __syncthreads();
    if (valid) {
      int pos = gbase[pid] + rank;
      idx[pid * TOK + pos] = i;
      gp[(size_t)pid * TOK + pos] = make_float2(r, s);
    }

  } else if (bid < PREP_ROUTE_B + PREP_CVTX_B) {
    size_t base = (size_t)(bid - PREP_ROUTE_B) * 1024 + threadIdx.x;  // float4 units
    const float4* xp = (const float4*)x;
#pragma unroll
    for (int q = 0; q < 4; ++q) {
      float4 v = xp[base + q * 256];
      alignas(8) unsigned short o4[4] = {f2bf(v.x), f2bf(v.y), f2bf(v.z), f2bf(v.w)};
      *(uint2*)(xs + (base + q * 256) * 4) = *(const uint2*)o4;
    }

  } else {
    int wb = bid - (PREP_ROUTE_B + PREP_CVTX_B);
    int e = wb >> 8, tt = wb & 255;
    int d0 = (tt >> 4) * 64, o0 = (tt & 15) * 64;
    const float* src = W + ((size_t)e << 20) + (size_t)d0 * OO + o0;
    for (int i = threadIdx.x; i < 1024; i += 256) {
      int r = i >> 4, c4 = (i & 15) * 4;
      float4 v = *(const float4*)(src + (size_t)r * OO + c4);
      tile[r][c4 + 0] = v.x; tile[r][c4 + 1] = v.y;
      tile[r][c4 + 2] = v.z; tile[r][c4 + 3] = v.w;
    }
    __syncthreads();
    unsigned short* dst = wtb + ((size_t)e << 20) + (size_t)o0 * DD + d0;
    for (int i = threadIdx.x; i < 512; i += 256) {
      int o = i >> 3, d8 = (i & 7) * 8;
      alignas(16) unsigned short w8[8];
#pragma unroll
      for (int j = 0; j < 8; ++j) w8[j] = f2bf(tile[d8 + j][o]);
      *(uint4*)(dst + (size_t)o * DD + d8) = *(const uint4*)w8;
    }
  }
}

// ---------------- grouped GEMM: 8-phase counted-vmcnt ----------------
__global__ __launch_bounds__(512) void moe_gemm(
    const unsigned short* __restrict__ xs,
    const unsigned short* __restrict__ wtb, const int* __restrict__ idx,
    const float2* __restrict__ gp, const int* __restrict__ cnt,
    const float* __restrict__ bias, float* __restrict__ out) {
  __shared__ unsigned short As[4 * A_HALF];   // 32 KB: 4 half-buffers
  __shared__ unsigned short Bs[4 * B_HALF];   // 64 KB
  __shared__ int    rowsS[BM];
  __shared__ float2 gS[BM];
  __shared__ int    sPid, sLt, sCnt;

  // derive (pid, local tile) from cnt[] with a 64-lane prefix scan
  if (threadIdx.x < 64) {
    int lane = threadIdx.x;
    if (lane == 0) sPid = -1;
    int c = cnt[lane];
    int n = (c + BM - 1) >> 7;
    int pre = n;
#pragma unroll
    for (int o = 1; o < 64; o <<= 1) {
      int v = __shfl_up(pre, o);
      if (lane >= o) pre += v;
    }
    int lo = pre - n;
    int tb = blockIdx.x;
    if (tb >= lo && tb < pre) { sPid = lane; sLt = tb - lo; sCnt = c; }
  }
  __syncthreads();
  int pid = sPid;
  if (pid < 0) return;
  int lt = sLt, cntv = sCnt;
  int e1 = pid >> 3, e2 = pid & 7;
  int n0 = blockIdx.y * BN;

  int t = threadIdx.x, lane = t & 63, w = t >> 6;   // w in 0..7
  if (t < BM) {
    int slot = lt * BM + t;
    int tok = 0; float2 g = make_float2(0.f, 0.f);
    if (slot < cntv) { tok = idx[pid * TOK + slot]; g = gp[(size_t)pid * TOK + slot]; }
    rowsS[t] = tok; gS[t] = g;
  }
  __syncthreads();   // drains all prior vmem; vmcnt==0 from here

  // stage sources (pre-swizzled global chunk: chunk' = chunk ^ ((row>>1)&3);
  // 64B rows / 4 chunks of 16B; LDS dest linear — same involution applied on read)
  int srcChunk = (((lane & 3) ^ ((lane >> 3) & 3)) << 3);   // elems
  int rA = w * 16 + (lane >> 2);                            // A row this lane stages
  const unsigned short* aSrc = xs + (size_t)rowsS[rA] * DD + srcChunk;
  int rB = w * 32 + (lane >> 2);                            // B rows: +0 and +16
  const unsigned short* bSrc = wtb + ((size_t)e1 * OO + n0 + rB) * DD + srcChunk;
  const ptrdiff_t bAdvE = (ptrdiff_t)(e2 - e1) * OO * DD;   // W[e1] -> W[e2]

  int wm = w >> 2, wn = w & 3;           // 2M x 4N wave grid
  int hi = lane >> 4, lo = lane & 15;
  int swz = ((hi ^ ((lo >> 1) & 3)) << 3);                  // read-side involution
  unsigned aBase = (unsigned)(uintptr_t)&As[0];             // LDS byte offsets
  unsigned bBase = (unsigned)(uintptr_t)&Bs[0];
  unsigned aOffB[4], bOffB[4];                              // byte offsets in half
#pragma unroll
  for (int m = 0; m < 4; ++m) aOffB[m] = ((wm * 64 + m * 16 + lo) * BKH + swz) * 2;
#pragma unroll
  for (int n = 0; n < 4; ++n) bOffB[n] = ((wn * 64 + n * 16 + lo) * BKH + swz) * 2;

  f32x4 acc[4][4] = {};

  // stage half h (h = 0..63; pass = h>>5, k-elems = (h&31)*32): 3 gloads/wave
  auto STAGE = [&](int h) {
    int hb = h & 3;
    size_t ko = (size_t)(h & 31) * BKH;
    const unsigned short* a = aSrc + ko;
    const unsigned short* b = bSrc + ko + ((h >= 32) ? bAdvE : (ptrdiff_t)0);
    gload_lds16(a, (unsigned short*)As + hb * A_HALF + w * 512);
    gload_lds16(b, (unsigned short*)Bs + hb * B_HALF + w * 1024);
    gload_lds16(b + (size_t)16 * DD, (unsigned short*)Bs + hb * B_HALF + w * 1024 + 512);
  };

  // phase: 8 asm ds_read || stage(h+3) -> bar -> lgkm(0) -> prio, 16 MFMA
  auto PHASE = [&](int h, int stageh) {
    unsigned hb = (unsigned)(h & 3);
    unsigned aB = aBase + hb * (A_HALF * 2);
    unsigned bB = bBase + hb * (B_HALF * 2);
    bf16x8 af[4], bv[4];
#pragma unroll
    for (int m = 0; m < 4; ++m) af[m] = ds_read_b128_bf16(aB + aOffB[m]);
#pragma unroll
    for (int n = 0; n < 4; ++n) bv[n] = ds_read_b128_bf16(bB + bOffB[n]);
    if (stageh >= 0) STAGE(stageh);
    __builtin_amdgcn_s_barrier();
    asm volatile("s_waitcnt lgkmcnt(0)" ::: "memory");
    __builtin_amdgcn_sched_barrier(0);
    __builtin_amdgcn_s_setprio(1);
#pragma unroll
    for (int m = 0; m < 4; ++m)
#pragma unroll
      for (int n = 0; n < 4; ++n)
        acc[m][n] = __builtin_amdgcn_mfma_f32_16x16x32_bf16(af[m], bv[n], acc[m][n], 0, 0, 0);
    __builtin_amdgcn_s_setprio(0);
    __builtin_amdgcn_sched_barrier(0);
  };

  // prologue: 3 half-tiles in flight (9 loads); confirm stage(0) -> 6 remain
  STAGE(0); STAGE(1); STAGE(2);
  ENDP(6);

#pragma unroll 1
  for (int h = 0; h < 31; ++h) { PHASE(h, h + 3); ENDP(6); }
  PHASE(31, 34); ENDP(6);
  // pass boundary: acc := r*(x*W1); pass 2 adds x*W2
#pragma unroll
  for (int m = 0; m < 4; ++m) {
    float rr[4];
#pragma unroll
    for (int j = 0; j < 4; ++j) rr[j] = gS[wm * 64 + m * 16 + hi * 4 + j].x;
#pragma unroll
    for (int n = 0; n < 4; ++n)
#pragma unroll
      for (int j = 0; j < 4; ++j) acc[m][n][j] *= rr[j];
  }
#pragma unroll 1
  for (int h = 32; h <= 60; ++h) { PHASE(h, h + 3); ENDP(6); }
  PHASE(61, -1); ENDP(3);
  PHASE(62, -1); ENDP(0);
  PHASE(63, -1);

  // epilogue: out = s*(acc + r*b1 + b2)
  const float* b1 = bias + e1 * OO;
  const float* b2 = bias + e2 * OO;
  float b1v[4], b2v[4];
#pragma unroll
  for (int n = 0; n < 4; ++n) {
    int col = n0 + wn * 64 + n * 16 + lo;
    b1v[n] = b1[col]; b2v[n] = b2[col];
  }
#pragma unroll
  for (int m = 0; m < 4; ++m) {
#pragma unroll
    for (int j = 0; j < 4; ++j) {
      int rl = wm * 64 + m * 16 + hi * 4 + j;   // C/D: row=(lane>>4)*4+reg, col=lane&15
      int slot = lt * BM + rl;
      if (slot < cntv) {
        float2 g = gS[rl];
        float* orow = out + (size_t)rowsS[rl] * OO + n0 + wn * 64 + lo;
#pragma unroll
        for (int n = 0; n < 4; ++n)
          orow[n * 16] = g.y * (acc[m][n][j] + g.x * b1v[n] + b2v[n]);
      }
    }
  }
}

extern "C" void kernel_launch(void* const* d_in, const int* in_sizes, int n_in,
                              void* d_out, int out_size, void* d_ws, size_t ws_size,
                              hipStream_t stream) {
  const float* x     = (const float*)d_in[0];
  const float* gates = (const float*)d_in[1];
  const float* W     = (const float*)d_in[2];
  const float* bias  = (const float*)d_in[3];
  float* out = (float*)d_out;

  char* ws = (char*)d_ws;
  size_t off = 0;
  unsigned short* xs  = (unsigned short*)(ws + off); off += (size_t)TOK * DD * 2;
  unsigned short* wtb = (unsigned short*)(ws + off); off += (size_t)NE * DD * OO * 2;
  int*    idx  = (int*)(ws + off);    off += (size_t)NBIN * TOK * 4;
  float2* gp   = (float2*)(ws + off); off += (size_t)NBIN * TOK * 8;
  int*    cnt  = (int*)(ws + off);    off += NBIN * 4;
  if (ws_size < off) return;  // insufficient scratch (~60.5 MB needed)

  hipMemsetAsync(cnt, 0, NBIN * 4, stream);
  prep<<<PREP_ROUTE_B + PREP_CVTX_B + PREP_CVTW_B, 256, 0, stream>>>(
      x, gates, W, xs, wtb, cnt, idx, gp);
  dim3 gg(MAXT, OO / BN, 1);   // tile in x: 192%8==0 -> col-blocks share XCD
  moe_gemm<<<gg, 512, 0, stream>>>(xs, wtb, idx, gp, cnt, bias, out);
}